// Round 12
// baseline (227.642 us; speedup 1.0000x reference)
//
#include <hip/hip_runtime.h>
#include <hip/hip_bf16.h>

typedef __attribute__((ext_vector_type(4))) float f32x4;
typedef __attribute__((ext_vector_type(8))) __bf16 bf16x8;
typedef __attribute__((ext_vector_type(4))) unsigned short us4;

static constexpr int BB = 2, SS = 2048, HID = 1024, NH = 16, HD = 64;
static constexpr int M_TOT = BB * SS;  // 4096

static __device__ __forceinline__ f32x4 mfma16(bf16x8 a, bf16x8 b, f32x4 c) {
  return __builtin_amdgcn_mfma_f32_16x16x32_bf16(a, b, c, 0, 0, 0);
}

static __device__ __forceinline__ unsigned short f2b(float x) {
  __hip_bfloat16 h = __float2bfloat16(x);
  unsigned short u;
  __builtin_memcpy(&u, &h, 2);
  return u;
}

static __device__ __forceinline__ float ex2(float x) {
  return __builtin_amdgcn_exp2f(x);  // raw v_exp_f32 (2^x)
}

// ---------------- f32 -> bf16 convert (x + 4 weights, one launch) ----------------
__global__ void cvt_all(const float* __restrict__ x,  const float* __restrict__ wq,
                        const float* __restrict__ wk, const float* __restrict__ wv,
                        const float* __restrict__ wo,
                        unsigned short* __restrict__ xb,  unsigned short* __restrict__ wqb,
                        unsigned short* __restrict__ wkb, unsigned short* __restrict__ wvb,
                        unsigned short* __restrict__ wob) {
  int y = blockIdx.y;
  const float* s; unsigned short* d; int n4;
  if (y == 0)      { s = x;  d = xb;  n4 = M_TOT * HID / 4; }
  else if (y == 1) { s = wq; d = wqb; n4 = HID * HID / 4; }
  else if (y == 2) { s = wk; d = wkb; n4 = HID * HID / 4; }
  else if (y == 3) { s = wv; d = wvb; n4 = HID * HID / 4; }
  else             { s = wo; d = wob; n4 = HID * HID / 4; }
  int idx = blockIdx.x * blockDim.x + threadIdx.x;
  int stride = gridDim.x * blockDim.x;
  const f32x4* sv = (const f32x4*)s;
  us4* dv = (us4*)d;
  for (int i = idx; i < n4; i += stride) {
    f32x4 v = sv[i];
    us4 o;
    o.x = f2b(v.x); o.y = f2b(v.y); o.z = f2b(v.z); o.w = f2b(v.w);
    dv[i] = o;
  }
}

// ---------------- shared GEMM mainloop (v2: double-buffered pipeline) ----------
// Port of attn's measured-working schedule: stage(t+1) -> counted vmcnt ->
// raw s_barrier -> compute(t) -> raw s_barrier (NO vmcnt drain in loop).
// Safety: every wave's ds_reads of buf[cur] complete (lgkmcnt waited before the
// consuming MFMA) before it reaches the bottom barrier, so re-staging into that
// buffer next iteration cannot race. MFMAs are register-only and may sink past
// the barrier harmlessly.
static __device__ __forceinline__ void stage_ab(
    const unsigned short* __restrict__ gA, const unsigned short* __restrict__ gB,
    int k0, unsigned short* As, unsigned short* Bs, int t) {
#pragma unroll
  for (int i_ = 0; i_ < 4; ++i_) {
    int chunk = i_ * 256 + t;           // 0..1023, 16B each
    int row = chunk >> 3;
    int col = (chunk & 7) << 3;
    __builtin_amdgcn_global_load_lds(
        (const __attribute__((address_space(1))) unsigned int*)(gA + (size_t)row * HID + k0 + col),
        (__attribute__((address_space(3))) unsigned int*)(As + chunk * 8), 16, 0, 0);
    __builtin_amdgcn_global_load_lds(
        (const __attribute__((address_space(1))) unsigned int*)(gB + (size_t)row * HID + k0 + col),
        (__attribute__((address_space(3))) unsigned int*)(Bs + chunk * 8), 16, 0, 0);
  }
}

static __device__ __forceinline__ void gemm_mainloop(
    const unsigned short* __restrict__ gA,  // tile base: rows m0.., [*, K=HID]
    const unsigned short* __restrict__ gB,  // tile base: rows n0.., [*, K=HID]
    unsigned short* As, unsigned short* Bs,  // each 2*8192 shorts (double buffer)
    int t, f32x4 acc[4][4]) {
  const int l = t & 63;
  const int lr = l & 15, lg = (l >> 4) & 3;
  const int w = t >> 6;
  const int wr = w >> 1, wc = w & 1;
  stage_ab(gA, gB, 0, As, Bs, t);
  int cur = 0;
  for (int k0 = 0; k0 < HID; k0 += 64) {
    if (k0 + 64 < HID) {
      stage_ab(gA, gB, k0 + 64, As + (cur ^ 1) * 8192, Bs + (cur ^ 1) * 8192, t);
      asm volatile("s_waitcnt vmcnt(8)" ::: "memory");  // tile t landed; t+1 in flight
    } else {
      asm volatile("s_waitcnt vmcnt(0)" ::: "memory");
    }
    __builtin_amdgcn_s_barrier();
    asm volatile("" ::: "memory");
    const unsigned short* Ac = As + cur * 8192;
    const unsigned short* Bc = Bs + cur * 8192;
#pragma unroll
    for (int kk = 0; kk < 2; ++kk) {
      bf16x8 a[4], bb[4];
#pragma unroll
      for (int mf = 0; mf < 4; ++mf)
        a[mf] = *(const bf16x8*)&Ac[(wr * 64 + mf * 16 + lr) * 64 + kk * 32 + lg * 8];
#pragma unroll
      for (int nf = 0; nf < 4; ++nf)
        bb[nf] = *(const bf16x8*)&Bc[(wc * 64 + nf * 16 + lr) * 64 + kk * 32 + lg * 8];
#pragma unroll
      for (int mf = 0; mf < 4; ++mf)
#pragma unroll
        for (int nf = 0; nf < 4; ++nf)
          acc[mf][nf] = mfma16(a[mf], bb[nf], acc[mf][nf]);
    }
    asm volatile("" ::: "memory");
    __builtin_amdgcn_s_barrier();   // raw: no drain; ds_reads already consumed
    cur ^= 1;
  }
}

// ---------------- fused QKV projection ----------------
// z=0: Q -> [B,NH,S,HD] bf16, scaled by 1/8
// z=1: K -> [B,NH,S,HD] bf16
// z=2: V -> [B,NH,HD,S] bf16 (transposed)
__global__ __launch_bounds__(256, 2) void qkv_gemm(
    const unsigned short* __restrict__ xb,
    const unsigned short* __restrict__ wqb, const unsigned short* __restrict__ wkb,
    const unsigned short* __restrict__ wvb,
    const float* __restrict__ bq, const float* __restrict__ bk, const float* __restrict__ bv,
    unsigned short* __restrict__ qo, unsigned short* __restrict__ ko,
    unsigned short* __restrict__ vto) {
  __shared__ unsigned short As[2 * 128 * 64];
  __shared__ unsigned short Bs[2 * 128 * 64];
  int t = threadIdx.x;
  int z = blockIdx.z;
  const unsigned short* Bmat = (z == 0) ? wqb : (z == 1) ? wkb : wvb;
  const float* bias = (z == 0) ? bq : (z == 1) ? bk : bv;
  int m0 = blockIdx.y * 128, n0 = blockIdx.x * 128;
  f32x4 acc[4][4] = {};
  gemm_mainloop(xb + (size_t)m0 * HID, Bmat + (size_t)n0 * HID, As, Bs, t, acc);

  int l = t & 63, lr = l & 15, lg = (l >> 4) & 3;
  int w = t >> 6, wr = w >> 1, wc = w & 1;
  float scale = (z == 0) ? 0.125f : 1.0f;
#pragma unroll
  for (int nf = 0; nf < 4; ++nf) {
    int n = n0 + wc * 64 + nf * 16 + lr;
    float bs = bias[n];
    int h = n >> 6, d = n & 63;
#pragma unroll
    for (int mf = 0; mf < 4; ++mf) {
#pragma unroll
      for (int j = 0; j < 4; ++j) {
        int m = m0 + wr * 64 + mf * 16 + lg * 4 + j;
        int b = m >> 11, sidx = m & (SS - 1);
        float val = (acc[mf][nf][j] + bs) * scale;
        unsigned short ob = f2b(val);
        if (z == 2)
          vto[((size_t)(b * NH + h) * HD + d) * SS + sidx] = ob;
        else {
          unsigned short* dst = (z == 0) ? qo : ko;
          dst[((size_t)(b * NH + h) * SS + sidx) * HD + d] = ob;
        }
      }
    }
  }
}

// ---------------- output projection (f32 out + bias) ----------------
__global__ __launch_bounds__(256, 2) void out_gemm(
    const unsigned short* __restrict__ Ab,  // [4096, 1024] bf16
    const unsigned short* __restrict__ Wb,  // [1024, 1024] bf16
    const float* __restrict__ bias,
    float* __restrict__ C) {                // [4096, 1024] f32
  __shared__ unsigned short As[2 * 128 * 64];
  __shared__ unsigned short Bs[2 * 128 * 64];
  int t = threadIdx.x;
  int m0 = blockIdx.y * 128, n0 = blockIdx.x * 128;
  f32x4 acc[4][4] = {};
  gemm_mainloop(Ab + (size_t)m0 * HID, Wb + (size_t)n0 * HID, As, Bs, t, acc);

  int l = t & 63, lr = l & 15, lg = (l >> 4) & 3;
  int w = t >> 6, wr = w >> 1, wc = w & 1;
#pragma unroll
  for (int nf = 0; nf < 4; ++nf) {
    int n = n0 + wc * 64 + nf * 16 + lr;
    float bs = bias[n];
#pragma unroll
    for (int mf = 0; mf < 4; ++mf) {
#pragma unroll
      for (int j = 0; j < 4; ++j) {
        int m = m0 + wr * 64 + mf * 16 + lg * 4 + j;
        C[(size_t)m * HID + n] = acc[mf][nf][j] + bs;
      }
    }
  }
}

// ---------------- flash attention with time-decay bias (v5, unchanged) ----------
static __device__ __forceinline__ void stage_kv(
    const unsigned short* __restrict__ kp, const unsigned short* __restrict__ vp,
    int kv0, unsigned short* Kd, unsigned short* Vd, int t) {
#pragma unroll
  for (int i_ = 0; i_ < 2; ++i_) {
    int chunk = i_ * 256 + t;          // 0..511, 16B each
    int row = chunk >> 3;              // 0..63
    int srcc = ((chunk & 7) ^ (row & 7)) << 3;  // inverse-swizzled src col
    __builtin_amdgcn_global_load_lds(
        (const __attribute__((address_space(1))) unsigned int*)(kp + (size_t)(kv0 + row) * HD + srcc),
        (__attribute__((address_space(3))) unsigned int*)(Kd + chunk * 8), 16, 0, 0);
    __builtin_amdgcn_global_load_lds(
        (const __attribute__((address_space(1))) unsigned int*)(vp + (size_t)row * SS + kv0 + srcc),
        (__attribute__((address_space(3))) unsigned int*)(Vd + chunk * 8), 16, 0, 0);
  }
}

__global__ __launch_bounds__(256, 2) void attn_kernel(
    const unsigned short* __restrict__ qg,   // [B,NH,S,HD] (Q pre-scaled by 1/8)
    const unsigned short* __restrict__ kg,   // [B,NH,S,HD]
    const unsigned short* __restrict__ vtg,  // [B,NH,HD,S]
    const float* __restrict__ td,            // [B,S]
    const float* __restrict__ decay,         // [NH]
    unsigned short* __restrict__ outb) {     // [B,S,HID] bf16
  __shared__ unsigned short Ks[2][64 * 64];  // swizzled [kv][d], double-buffered
  __shared__ unsigned short Vs[2][64 * 64];  // swizzled [d][kv]
  __shared__ unsigned short Pl[4][16][64];   // per-wave P, XOR-swizzled cols
  const int t = threadIdx.x;
  const int l = t & 63;
  const int w = t >> 6;
  const int lr = l & 15, lg = (l >> 4) & 3;
  const int L = blockIdx.x;
  const int W = (L & 7) * 64 + (L >> 3);
  const int xp = W & 15;                     // pair index
  const int h = (W >> 4) & 15;
  const int b = W >> 8;
  const unsigned short* qp = qg + ((size_t)(b * NH + h) * SS) * HD;
  const unsigned short* kp = kg + ((size_t)(b * NH + h) * SS) * HD;
  const unsigned short* vp = vtg + ((size_t)(b * NH + h) * HD) * SS;
  const float* tdb = td + (size_t)b * SS;
  const float dec = decay[h];
  const float L2E = 1.44269504f;
  const float dl = dec * L2E;
  const float SHIFT = 16.0f;                 // constant softmax shift (exp2 units)

  for (int seg = 0; seg < 2; ++seg) {
    const int qb = seg ? 31 - xp : xp;
    const int q0 = qb * 64;
    const int qw = q0 + w * 16;             // this wave's q start

    bf16x8 qf0 = *(const bf16x8*)&qp[(size_t)(qw + lr) * HD + lg * 8];
    bf16x8 qf1 = *(const bf16x8*)&qp[(size_t)(qw + lr) * HD + 32 + lg * 8];
    float eqL[4], fqL[4];
#pragma unroll
    for (int j = 0; j < 4; ++j) {
      float tq = tdb[qw + lg * 4 + j];
      eqL[j] = ex2(dl * tq) * L2E;   // log2e folded in: exponent = s*wL
      fqL[j] = ex2(-dl * tq) * L2E;
    }
    float lsum[4] = {0.f, 0.f, 0.f, 0.f};
    f32x4 o[4] = {};

    stage_kv(kp, vp, 0, Ks[0], Vs[0], t);
    int cur = 0;
    for (int tkv = 0; tkv <= qb; ++tkv) {
      const int kv0 = tkv * 64;
      if (tkv < qb) {
        stage_kv(kp, vp, kv0 + 64, Ks[cur ^ 1], Vs[cur ^ 1], t);
        asm volatile("s_waitcnt vmcnt(4)" ::: "memory");
      } else {
        asm volatile("s_waitcnt vmcnt(0)" ::: "memory");
      }
      __builtin_amdgcn_s_barrier();
      asm volatile("" ::: "memory");
      const unsigned short* Kc = Ks[cur];
      const unsigned short* Vc = Vs[cur];

      // ---- QK^T: S[16,64] = Q[16,64] x K[64,64]^T ----
      f32x4 s[4];
#pragma unroll
      for (int nf = 0; nf < 4; ++nf) {
        int r = nf * 16 + lr;
        bf16x8 kf0 = *(const bf16x8*)&Kc[r * 64 + ((lg ^ (r & 7)) << 3)];
        bf16x8 kf1 = *(const bf16x8*)&Kc[r * 64 + (((4 + lg) ^ (r & 7)) << 3)];
        f32x4 zz = {};
        zz = mfma16(qf0, kf0, zz);
        s[nf] = mfma16(qf1, kf1, zz);
      }
      // ---- decay weight + constant-shift exp2 softmax numerator ----
      const bool diag = (tkv == qb);
#pragma unroll
      for (int nf = 0; nf < 4; ++nf) {
        int col = kv0 + nf * 16 + lr;
        float tk = tdb[col];
        float ek = ex2(dl * tk);
        float fk = ex2(-dl * tk);
#pragma unroll
        for (int j = 0; j < 4; ++j) {
          int row = lg * 4 + j;
          float wL = fminf(eqL[j] * fk, fqL[j] * ek);  // w * log2e
          float pv = ex2(s[nf][j] * wL - SHIFT);
          if (diag && col > qw + row) pv = 0.f;        // causal (diag tile only)
          lsum[j] += pv;
          Pl[w][row][(nf * 16 + lr) ^ ((row & 7) << 3)] = f2b(pv);
        }
      }
      // ---- PV: O[16,64] += P[16,64] x V[64,64] ----
#pragma unroll
      for (int kk = 0; kk < 2; ++kk) {
        bf16x8 pa = *(const bf16x8*)&Pl[w][lr][(kk * 32 + lg * 8) ^ ((lr & 7) << 3)];
        int g = kk * 4 + lg;
#pragma unroll
        for (int df = 0; df < 4; ++df) {
          int r = df * 16 + lr;
          bf16x8 vf = *(const bf16x8*)&Vc[r * 64 + ((g ^ (r & 7)) << 3)];
          o[df] = mfma16(pa, vf, o[df]);
        }
      }
      __syncthreads();
      cur ^= 1;
    }
    // epilogue: one cross-lane sum of lsum per row, divide, store bf16
#pragma unroll
    for (int j = 0; j < 4; ++j) {
      float rs = lsum[j];
      rs += __shfl_xor(rs, 1, 16);
      rs += __shfl_xor(rs, 2, 16);
      rs += __shfl_xor(rs, 4, 16);
      rs += __shfl_xor(rs, 8, 16);
      float inv = 1.0f / rs;
      int srow = qw + lg * 4 + j;
#pragma unroll
      for (int df = 0; df < 4; ++df)
        outb[((size_t)b * SS + srow) * HID + h * HD + df * 16 + lr] = f2b(o[df][j] * inv);
    }
  }
}

extern "C" void kernel_launch(void* const* d_in, const int* in_sizes, int n_in,
                              void* d_out, int out_size, void* d_ws, size_t ws_size,
                              hipStream_t stream) {
  const float* x    = (const float*)d_in[0];
  const float* td   = (const float*)d_in[1];
  const float* Wq   = (const float*)d_in[2];
  const float* bq   = (const float*)d_in[3];
  const float* Wk   = (const float*)d_in[4];
  const float* bk   = (const float*)d_in[5];
  const float* Wv   = (const float*)d_in[6];
  const float* bv   = (const float*)d_in[7];
  const float* Wo   = (const float*)d_in[8];
  const float* bo   = (const float*)d_in[9];
  const float* tdec = (const float*)d_in[10];
  float* out = (float*)d_out;

  char* ws = (char*)d_ws;
  unsigned short* xb  = (unsigned short*)ws; ws += (size_t)M_TOT * HID * 2;  // 8 MB
  unsigned short* wqb = (unsigned short*)ws; ws += (size_t)HID * HID * 2;    // 2 MB
  unsigned short* wkb = (unsigned short*)ws; ws += (size_t)HID * HID * 2;
  unsigned short* wvb = (unsigned short*)ws; ws += (size_t)HID * HID * 2;
  unsigned short* wob = (unsigned short*)ws; ws += (size_t)HID * HID * 2;
  unsigned short* qb  = (unsigned short*)ws; ws += (size_t)M_TOT * HID * 2;  // 8 MB
  unsigned short* kb  = (unsigned short*)ws; ws += (size_t)M_TOT * HID * 2;
  unsigned short* vtb = (unsigned short*)ws; ws += (size_t)M_TOT * HID * 2;
  unsigned short* ob  = (unsigned short*)ws; ws += (size_t)M_TOT * HID * 2;

  cvt_all<<<dim3(512, 5), 256, 0, stream>>>(x, Wq, Wk, Wv, Wo, xb, wqb, wkb, wvb, wob);
  qkv_gemm<<<dim3(HID / 128, M_TOT / 128, 3), 256, 0, stream>>>(
      xb, wqb, wkb, wvb, bq, bk, bv, qb, kb, vtb);
  attn_kernel<<<512, 256, 0, stream>>>(qb, kb, vtb, td, tdec, ob);
  out_gemm<<<dim3(HID / 128, M_TOT / 128), 256, 0, stream>>>(ob, wob, bo, out);
}

// Round 14
// 196.975 us; speedup vs baseline: 1.1557x; 1.1557x over previous
//
#include <hip/hip_runtime.h>
#include <hip/hip_bf16.h>

typedef __attribute__((ext_vector_type(4))) float f32x4;
typedef __attribute__((ext_vector_type(8))) __bf16 bf16x8;
typedef __attribute__((ext_vector_type(4))) unsigned short us4;

static constexpr int BB = 2, SS = 2048, HID = 1024, NH = 16, HD = 64;
static constexpr int M_TOT = BB * SS;  // 4096

static __device__ __forceinline__ f32x4 mfma16(bf16x8 a, bf16x8 b, f32x4 c) {
  return __builtin_amdgcn_mfma_f32_16x16x32_bf16(a, b, c, 0, 0, 0);
}

static __device__ __forceinline__ unsigned short f2b(float x) {
  __hip_bfloat16 h = __float2bfloat16(x);
  unsigned short u;
  __builtin_memcpy(&u, &h, 2);
  return u;
}

static __device__ __forceinline__ float ex2(float x) {
  return __builtin_amdgcn_exp2f(x);  // raw v_exp_f32 (2^x)
}

// ---------------- f32 -> bf16 convert (x + 4 weights, one launch) ----------------
__global__ void cvt_all(const float* __restrict__ x,  const float* __restrict__ wq,
                        const float* __restrict__ wk, const float* __restrict__ wv,
                        const float* __restrict__ wo,
                        unsigned short* __restrict__ xb,  unsigned short* __restrict__ wqb,
                        unsigned short* __restrict__ wkb, unsigned short* __restrict__ wvb,
                        unsigned short* __restrict__ wob) {
  int y = blockIdx.y;
  const float* s; unsigned short* d; int n4;
  if (y == 0)      { s = x;  d = xb;  n4 = M_TOT * HID / 4; }
  else if (y == 1) { s = wq; d = wqb; n4 = HID * HID / 4; }
  else if (y == 2) { s = wk; d = wkb; n4 = HID * HID / 4; }
  else if (y == 3) { s = wv; d = wvb; n4 = HID * HID / 4; }
  else             { s = wo; d = wob; n4 = HID * HID / 4; }
  int idx = blockIdx.x * blockDim.x + threadIdx.x;
  int stride = gridDim.x * blockDim.x;
  const f32x4* sv = (const f32x4*)s;
  us4* dv = (us4*)d;
  for (int i = idx; i < n4; i += stride) {
    f32x4 v = sv[i];
    us4 o;
    o.x = f2b(v.x); o.y = f2b(v.y); o.z = f2b(v.z); o.w = f2b(v.w);
    dv[i] = o;
  }
}

// ---------------- shared GEMM mainloop (v3: single-buffer + XOR swizzle) --------
// Round-11 proven structure (stage -> sync -> compute -> sync; 32KB LDS keeps
// 4+ blocks/CU whose wave-level overlap hides stage latency — m114/m99 lesson),
// plus both-sides XOR swizzle (rule #21: inverse-swizzled GLOBAL source, linear
// LDS dest via global_load_lds, swizzled read) to kill the 16-way bank conflict
// of 128B-row-stride ds_read_b128 (was 9.4M conflicts/dispatch).
static __device__ __forceinline__ void stage_ab(
    const unsigned short* __restrict__ gA, const unsigned short* __restrict__ gB,
    int k0, unsigned short* As, unsigned short* Bs, int t) {
#pragma unroll
  for (int i_ = 0; i_ < 4; ++i_) {
    int chunk = i_ * 256 + t;           // 0..1023, 16B each
    int row = chunk >> 3;               // 0..127
    int srcc = ((chunk & 7) ^ (row & 7)) << 3;  // inverse-swizzled src col (elems)
    __builtin_amdgcn_global_load_lds(
        (const __attribute__((address_space(1))) unsigned int*)(gA + (size_t)row * HID + k0 + srcc),
        (__attribute__((address_space(3))) unsigned int*)(As + chunk * 8), 16, 0, 0);
    __builtin_amdgcn_global_load_lds(
        (const __attribute__((address_space(1))) unsigned int*)(gB + (size_t)row * HID + k0 + srcc),
        (__attribute__((address_space(3))) unsigned int*)(Bs + chunk * 8), 16, 0, 0);
  }
}

static __device__ __forceinline__ void gemm_mainloop(
    const unsigned short* __restrict__ gA,  // tile base: rows m0.., [*, K=HID]
    const unsigned short* __restrict__ gB,  // tile base: rows n0.., [*, K=HID]
    unsigned short* As, unsigned short* Bs, int t, f32x4 acc[4][4]) {
  const int l = t & 63;
  const int lr = l & 15, lg = (l >> 4) & 3;
  const int w = t >> 6;
  const int wr = w >> 1, wc = w & 1;
  for (int k0 = 0; k0 < HID; k0 += 64) {
    stage_ab(gA, gB, k0, As, Bs, t);
    __syncthreads();
#pragma unroll
    for (int kk = 0; kk < 2; ++kk) {
      bf16x8 a[4], bb[4];
#pragma unroll
      for (int mf = 0; mf < 4; ++mf) {
        int r = wr * 64 + mf * 16 + lr;
        a[mf] = *(const bf16x8*)&As[r * 64 + (((kk * 4 + lg) ^ (lr & 7)) << 3)];
      }
#pragma unroll
      for (int nf = 0; nf < 4; ++nf) {
        int r = wc * 64 + nf * 16 + lr;
        bb[nf] = *(const bf16x8*)&Bs[r * 64 + (((kk * 4 + lg) ^ (lr & 7)) << 3)];
      }
#pragma unroll
      for (int mf = 0; mf < 4; ++mf)
#pragma unroll
        for (int nf = 0; nf < 4; ++nf)
          acc[mf][nf] = mfma16(a[mf], bb[nf], acc[mf][nf]);
    }
    __syncthreads();
  }
}

// ---------------- fused QKV projection ----------------
// z=0: Q -> [B,NH,S,HD] bf16, scaled by 1/8
// z=1: K -> [B,NH,S,HD] bf16
// z=2: V -> [B,NH,HD,S] bf16 (transposed)
__global__ __launch_bounds__(256, 2) void qkv_gemm(
    const unsigned short* __restrict__ xb,
    const unsigned short* __restrict__ wqb, const unsigned short* __restrict__ wkb,
    const unsigned short* __restrict__ wvb,
    const float* __restrict__ bq, const float* __restrict__ bk, const float* __restrict__ bv,
    unsigned short* __restrict__ qo, unsigned short* __restrict__ ko,
    unsigned short* __restrict__ vto) {
  __shared__ unsigned short As[128 * 64];
  __shared__ unsigned short Bs[128 * 64];
  int t = threadIdx.x;
  int z = blockIdx.z;
  const unsigned short* Bmat = (z == 0) ? wqb : (z == 1) ? wkb : wvb;
  const float* bias = (z == 0) ? bq : (z == 1) ? bk : bv;
  int m0 = blockIdx.y * 128, n0 = blockIdx.x * 128;
  f32x4 acc[4][4] = {};
  gemm_mainloop(xb + (size_t)m0 * HID, Bmat + (size_t)n0 * HID, As, Bs, t, acc);

  int l = t & 63, lr = l & 15, lg = (l >> 4) & 3;
  int w = t >> 6, wr = w >> 1, wc = w & 1;
  float scale = (z == 0) ? 0.125f : 1.0f;
#pragma unroll
  for (int nf = 0; nf < 4; ++nf) {
    int n = n0 + wc * 64 + nf * 16 + lr;
    float bs = bias[n];
    int h = n >> 6, d = n & 63;
#pragma unroll
    for (int mf = 0; mf < 4; ++mf) {
#pragma unroll
      for (int j = 0; j < 4; ++j) {
        int m = m0 + wr * 64 + mf * 16 + lg * 4 + j;
        int b = m >> 11, sidx = m & (SS - 1);
        float val = (acc[mf][nf][j] + bs) * scale;
        unsigned short ob = f2b(val);
        if (z == 2)
          vto[((size_t)(b * NH + h) * HD + d) * SS + sidx] = ob;
        else {
          unsigned short* dst = (z == 0) ? qo : ko;
          dst[((size_t)(b * NH + h) * SS + sidx) * HD + d] = ob;
        }
      }
    }
  }
}

// ---------------- output projection (f32 out + bias) ----------------
__global__ __launch_bounds__(256, 2) void out_gemm(
    const unsigned short* __restrict__ Ab,  // [4096, 1024] bf16
    const unsigned short* __restrict__ Wb,  // [1024, 1024] bf16
    const float* __restrict__ bias,
    float* __restrict__ C) {                // [4096, 1024] f32
  __shared__ unsigned short As[128 * 64];
  __shared__ unsigned short Bs[128 * 64];
  int t = threadIdx.x;
  int m0 = blockIdx.y * 128, n0 = blockIdx.x * 128;
  f32x4 acc[4][4] = {};
  gemm_mainloop(Ab + (size_t)m0 * HID, Wb + (size_t)n0 * HID, As, Bs, t, acc);

  int l = t & 63, lr = l & 15, lg = (l >> 4) & 3;
  int w = t >> 6, wr = w >> 1, wc = w & 1;
#pragma unroll
  for (int nf = 0; nf < 4; ++nf) {
    int n = n0 + wc * 64 + nf * 16 + lr;
    float bs = bias[n];
#pragma unroll
    for (int mf = 0; mf < 4; ++mf) {
#pragma unroll
      for (int j = 0; j < 4; ++j) {
        int m = m0 + wr * 64 + mf * 16 + lg * 4 + j;
        C[(size_t)m * HID + n] = acc[mf][nf][j] + bs;
      }
    }
  }
}

// ---------------- flash attention with time-decay bias (v5, unchanged) ----------
static __device__ __forceinline__ void stage_kv(
    const unsigned short* __restrict__ kp, const unsigned short* __restrict__ vp,
    int kv0, unsigned short* Kd, unsigned short* Vd, int t) {
#pragma unroll
  for (int i_ = 0; i_ < 2; ++i_) {
    int chunk = i_ * 256 + t;          // 0..511, 16B each
    int row = chunk >> 3;              // 0..63
    int srcc = ((chunk & 7) ^ (row & 7)) << 3;  // inverse-swizzled src col
    __builtin_amdgcn_global_load_lds(
        (const __attribute__((address_space(1))) unsigned int*)(kp + (size_t)(kv0 + row) * HD + srcc),
        (__attribute__((address_space(3))) unsigned int*)(Kd + chunk * 8), 16, 0, 0);
    __builtin_amdgcn_global_load_lds(
        (const __attribute__((address_space(1))) unsigned int*)(vp + (size_t)row * SS + kv0 + srcc),
        (__attribute__((address_space(3))) unsigned int*)(Vd + chunk * 8), 16, 0, 0);
  }
}

__global__ __launch_bounds__(256, 2) void attn_kernel(
    const unsigned short* __restrict__ qg,   // [B,NH,S,HD] (Q pre-scaled by 1/8)
    const unsigned short* __restrict__ kg,   // [B,NH,S,HD]
    const unsigned short* __restrict__ vtg,  // [B,NH,HD,S]
    const float* __restrict__ td,            // [B,S]
    const float* __restrict__ decay,         // [NH]
    unsigned short* __restrict__ outb) {     // [B,S,HID] bf16
  __shared__ unsigned short Ks[2][64 * 64];  // swizzled [kv][d], double-buffered
  __shared__ unsigned short Vs[2][64 * 64];  // swizzled [d][kv]
  __shared__ unsigned short Pl[4][16][64];   // per-wave P, XOR-swizzled cols
  const int t = threadIdx.x;
  const int l = t & 63;
  const int w = t >> 6;
  const int lr = l & 15, lg = (l >> 4) & 3;
  const int L = blockIdx.x;
  const int W = (L & 7) * 64 + (L >> 3);
  const int xp = W & 15;                     // pair index
  const int h = (W >> 4) & 15;
  const int b = W >> 8;
  const unsigned short* qp = qg + ((size_t)(b * NH + h) * SS) * HD;
  const unsigned short* kp = kg + ((size_t)(b * NH + h) * SS) * HD;
  const unsigned short* vp = vtg + ((size_t)(b * NH + h) * HD) * SS;
  const float* tdb = td + (size_t)b * SS;
  const float dec = decay[h];
  const float L2E = 1.44269504f;
  const float dl = dec * L2E;
  const float SHIFT = 16.0f;                 // constant softmax shift (exp2 units)

  for (int seg = 0; seg < 2; ++seg) {
    const int qb = seg ? 31 - xp : xp;
    const int q0 = qb * 64;
    const int qw = q0 + w * 16;             // this wave's q start

    bf16x8 qf0 = *(const bf16x8*)&qp[(size_t)(qw + lr) * HD + lg * 8];
    bf16x8 qf1 = *(const bf16x8*)&qp[(size_t)(qw + lr) * HD + 32 + lg * 8];
    float eqL[4], fqL[4];
#pragma unroll
    for (int j = 0; j < 4; ++j) {
      float tq = tdb[qw + lg * 4 + j];
      eqL[j] = ex2(dl * tq) * L2E;   // log2e folded in: exponent = s*wL
      fqL[j] = ex2(-dl * tq) * L2E;
    }
    float lsum[4] = {0.f, 0.f, 0.f, 0.f};
    f32x4 o[4] = {};

    stage_kv(kp, vp, 0, Ks[0], Vs[0], t);
    int cur = 0;
    for (int tkv = 0; tkv <= qb; ++tkv) {
      const int kv0 = tkv * 64;
      if (tkv < qb) {
        stage_kv(kp, vp, kv0 + 64, Ks[cur ^ 1], Vs[cur ^ 1], t);
        asm volatile("s_waitcnt vmcnt(4)" ::: "memory");
      } else {
        asm volatile("s_waitcnt vmcnt(0)" ::: "memory");
      }
      __builtin_amdgcn_s_barrier();
      asm volatile("" ::: "memory");
      const unsigned short* Kc = Ks[cur];
      const unsigned short* Vc = Vs[cur];

      // ---- QK^T: S[16,64] = Q[16,64] x K[64,64]^T ----
      f32x4 s[4];
#pragma unroll
      for (int nf = 0; nf < 4; ++nf) {
        int r = nf * 16 + lr;
        bf16x8 kf0 = *(const bf16x8*)&Kc[r * 64 + ((lg ^ (r & 7)) << 3)];
        bf16x8 kf1 = *(const bf16x8*)&Kc[r * 64 + (((4 + lg) ^ (r & 7)) << 3)];
        f32x4 zz = {};
        zz = mfma16(qf0, kf0, zz);
        s[nf] = mfma16(qf1, kf1, zz);
      }
      // ---- decay weight + constant-shift exp2 softmax numerator ----
      const bool diag = (tkv == qb);
#pragma unroll
      for (int nf = 0; nf < 4; ++nf) {
        int col = kv0 + nf * 16 + lr;
        float tk = tdb[col];
        float ek = ex2(dl * tk);
        float fk = ex2(-dl * tk);
#pragma unroll
        for (int j = 0; j < 4; ++j) {
          int row = lg * 4 + j;
          float wL = fminf(eqL[j] * fk, fqL[j] * ek);  // w * log2e
          float pv = ex2(s[nf][j] * wL - SHIFT);
          if (diag && col > qw + row) pv = 0.f;        // causal (diag tile only)
          lsum[j] += pv;
          Pl[w][row][(nf * 16 + lr) ^ ((row & 7) << 3)] = f2b(pv);
        }
      }
      // ---- PV: O[16,64] += P[16,64] x V[64,64] ----
#pragma unroll
      for (int kk = 0; kk < 2; ++kk) {
        bf16x8 pa = *(const bf16x8*)&Pl[w][lr][(kk * 32 + lg * 8) ^ ((lr & 7) << 3)];
        int g = kk * 4 + lg;
#pragma unroll
        for (int df = 0; df < 4; ++df) {
          int r = df * 16 + lr;
          bf16x8 vf = *(const bf16x8*)&Vc[r * 64 + ((g ^ (r & 7)) << 3)];
          o[df] = mfma16(pa, vf, o[df]);
        }
      }
      __syncthreads();
      cur ^= 1;
    }
    // epilogue: one cross-lane sum of lsum per row, divide, store bf16
#pragma unroll
    for (int j = 0; j < 4; ++j) {
      float rs = lsum[j];
      rs += __shfl_xor(rs, 1, 16);
      rs += __shfl_xor(rs, 2, 16);
      rs += __shfl_xor(rs, 4, 16);
      rs += __shfl_xor(rs, 8, 16);
      float inv = 1.0f / rs;
      int srow = qw + lg * 4 + j;
#pragma unroll
      for (int df = 0; df < 4; ++df)
        outb[((size_t)b * SS + srow) * HID + h * HD + df * 16 + lr] = f2b(o[df][j] * inv);
    }
  }
}

extern "C" void kernel_launch(void* const* d_in, const int* in_sizes, int n_in,
                              void* d_out, int out_size, void* d_ws, size_t ws_size,
                              hipStream_t stream) {
  const float* x    = (const float*)d_in[0];
  const float* td   = (const float*)d_in[1];
  const float* Wq   = (const float*)d_in[2];
  const float* bq   = (const float*)d_in[3];
  const float* Wk   = (const float*)d_in[4];
  const float* bk   = (const float*)d_in[5];
  const float* Wv   = (const float*)d_in[6];
  const float* bv   = (const float*)d_in[7];
  const float* Wo   = (const float*)d_in[8];
  const float* bo   = (const float*)d_in[9];
  const float* tdec = (const float*)d_in[10];
  float* out = (float*)d_out;

  char* ws = (char*)d_ws;
  unsigned short* xb  = (unsigned short*)ws; ws += (size_t)M_TOT * HID * 2;  // 8 MB
  unsigned short* wqb = (unsigned short*)ws; ws += (size_t)HID * HID * 2;    // 2 MB
  unsigned short* wkb = (unsigned short*)ws; ws += (size_t)HID * HID * 2;
  unsigned short* wvb = (unsigned short*)ws; ws += (size_t)HID * HID * 2;
  unsigned short* wob = (unsigned short*)ws; ws += (size_t)HID * HID * 2;
  unsigned short* qb  = (unsigned short*)ws; ws += (size_t)M_TOT * HID * 2;  // 8 MB
  unsigned short* kb  = (unsigned short*)ws; ws += (size_t)M_TOT * HID * 2;
  unsigned short* vtb = (unsigned short*)ws; ws += (size_t)M_TOT * HID * 2;
  unsigned short* ob  = (unsigned short*)ws; ws += (size_t)M_TOT * HID * 2;

  cvt_all<<<dim3(512, 5), 256, 0, stream>>>(x, Wq, Wk, Wv, Wo, xb, wqb, wkb, wvb, wob);
  qkv_gemm<<<dim3(HID / 128, M_TOT / 128, 3), 256, 0, stream>>>(
      xb, wqb, wkb, wvb, bq, bk, bv, qb, kb, vtb);
  attn_kernel<<<512, 256, 0, stream>>>(qb, kb, vtb, td, tdec, ob);
  out_gemm<<<dim3(HID / 128, M_TOT / 128), 256, 0, stream>>>(ob, wob, bo, out);
}